// Round 15
// baseline (3523.527 us; speedup 1.0000x reference)
//
#include <hip/hip_runtime.h>
#include <cmath>

// RNN: T=2048, B=64, I=H=512, fp32 in/out.
// Phase 0: w_prep  — pre-convert W_hh chunks 8..11 to f16 frag table in d_ws.
// Phase 1: xw_gemm — f16-MFMA GEMM: xw = x @ W_ih^T + (b_ih+b_hh) -> d_out.
// Phase 2: rnn_scan — R14 structure + CROSS-STEP PIPELINE:
//   consume L2-staged chunks 8..11 FIRST (loaded during previous step), then
//   issue their reloads for step t+1 (~1800 cy of cover), then AGPR chunks
//   0..7, then LDS chunks 12..15. lgkm-only barrier so reloads + h-store ack
//   stay in flight across the step boundary (no vmcnt drain).

#define SEQ_T 2048
#define BATCH 64
#define KDIM 512
#define HDIM 512

typedef __fp16 h2v __attribute__((ext_vector_type(2)));
typedef __fp16 f16x8 __attribute__((ext_vector_type(8)));
typedef float f32x4 __attribute__((ext_vector_type(4)));

static __device__ __forceinline__ f16x8 pk8(float4 a, float4 b) {
  h2v p0 = __builtin_amdgcn_cvt_pkrtz(a.x, a.y);
  h2v p1 = __builtin_amdgcn_cvt_pkrtz(a.z, a.w);
  h2v p2 = __builtin_amdgcn_cvt_pkrtz(b.x, b.y);
  h2v p3 = __builtin_amdgcn_cvt_pkrtz(b.z, b.w);
  f16x8 r;
  r[0] = p0[0]; r[1] = p0[1]; r[2] = p1[0]; r[3] = p1[1];
  r[4] = p2[0]; r[5] = p2[1]; r[6] = p3[0]; r[7] = p3[1];
  return r;
}

// ================= Phase 0: prep f16 fragment table (chunks 8..11) ==========
// frag(n=8..11, c=0..3, w=0..7, l=0..63) = W[64w+16c+(l&15)][32n+8(l>>4)+e]
// ws index = ((n-8)*4 + c)*512 + w*64 + l   (f16x8 units)
__global__ __launch_bounds__(256) void w_prep(const float* __restrict__ Whh,
                                              f16x8* __restrict__ ws) {
  int v = blockIdx.x * 256 + threadIdx.x;  // 8192 total
  int l = v & 63, w = (v >> 6) & 7, c = (v >> 9) & 3, n = (v >> 11) + 8;
  int row = 64 * w + 16 * c + (l & 15);
  int col = 32 * n + 8 * (l >> 4);
  const float* p = Whh + (size_t)row * KDIM + col;
  ws[v] = pk8(*(const float4*)p, *(const float4*)(p + 4));
}

// ================= Phase 1: f16 MFMA GEMM ===================================
#define G_LDA 72  // f16 units per row (144 B)

#define MFM(mt, nt) \
  d##mt##nt = __builtin_amdgcn_mfma_f32_16x16x32_f16(fa##mt, fb##nt, d##mt##nt, 0, 0, 0);

#define EPI(mt, nt, bb)                                                     \
  {                                                                         \
    int row = m0 + wm + mt * 16 + (l >> 4) * 4;                             \
    int col = n0 + wn + nt * 16 + (l & 15);                                 \
    out[(size_t)(row + 0) * HDIM + col] = d##mt##nt[0] + bb;                \
    out[(size_t)(row + 1) * HDIM + col] = d##mt##nt[1] + bb;                \
    out[(size_t)(row + 2) * HDIM + col] = d##mt##nt[2] + bb;                \
    out[(size_t)(row + 3) * HDIM + col] = d##mt##nt[3] + bb;                \
  }

__global__ __launch_bounds__(256) void xw_gemm(const float* __restrict__ x,
                                               const float* __restrict__ Wih,
                                               const float* __restrict__ bih,
                                               const float* __restrict__ bhh,
                                               float* __restrict__ out) {
  __shared__ __fp16 At[128 * G_LDA];
  __shared__ __fp16 Bt[64 * G_LDA];
  const int tid = threadIdx.x;
  const int l = tid & 63;
  const int w = tid >> 6;
  const int m0 = (blockIdx.x >> 3) * 128;
  const int n0 = (blockIdx.x & 7) * 64;
  const int wm = (w >> 1) * 64;
  const int wn = (w & 1) * 32;

  const float bias0 = bih[n0 + wn + (l & 15)] + bhh[n0 + wn + (l & 15)];
  const float bias1 = bih[n0 + wn + 16 + (l & 15)] + bhh[n0 + wn + 16 + (l & 15)];

  f32x4 d00 = {0,0,0,0}, d01 = {0,0,0,0}, d10 = {0,0,0,0}, d11 = {0,0,0,0};
  f32x4 d20 = {0,0,0,0}, d21 = {0,0,0,0}, d30 = {0,0,0,0}, d31 = {0,0,0,0};

  for (int k0 = 0; k0 < KDIM; k0 += 64) {
    __syncthreads();
#pragma unroll
    for (int p = 0; p < 4; ++p) {
      int idx = tid + p * 256;
      int r = idx >> 3, sg = idx & 7;
      const float* ps = x + (size_t)(m0 + r) * KDIM + k0 + sg * 8;
      *(f16x8*)(At + r * G_LDA + sg * 8) =
          pk8(*(const float4*)ps, *(const float4*)(ps + 4));
    }
#pragma unroll
    for (int p = 0; p < 2; ++p) {
      int idx = tid + p * 256;
      int r = idx >> 3, sg = idx & 7;
      const float* ps = Wih + (size_t)(n0 + r) * KDIM + k0 + sg * 8;
      *(f16x8*)(Bt + r * G_LDA + sg * 8) =
          pk8(*(const float4*)ps, *(const float4*)(ps + 4));
    }
    __syncthreads();
#pragma unroll
    for (int kk = 0; kk < 2; ++kk) {
      const int kc = kk * 32 + (l >> 4) * 8;
      f16x8 fa0 = *(const f16x8*)(At + (wm + 0 * 16 + (l & 15)) * G_LDA + kc);
      f16x8 fa1 = *(const f16x8*)(At + (wm + 1 * 16 + (l & 15)) * G_LDA + kc);
      f16x8 fa2 = *(const f16x8*)(At + (wm + 2 * 16 + (l & 15)) * G_LDA + kc);
      f16x8 fa3 = *(const f16x8*)(At + (wm + 3 * 16 + (l & 15)) * G_LDA + kc);
      f16x8 fb0 = *(const f16x8*)(Bt + (wn + 0 * 16 + (l & 15)) * G_LDA + kc);
      f16x8 fb1 = *(const f16x8*)(Bt + (wn + 1 * 16 + (l & 15)) * G_LDA + kc);
      MFM(0, 0) MFM(1, 0) MFM(2, 0) MFM(3, 0)
      MFM(0, 1) MFM(1, 1) MFM(2, 1) MFM(3, 1)
    }
  }

  EPI(0, 0, bias0) EPI(1, 0, bias0) EPI(2, 0, bias0) EPI(3, 0, bias0)
  EPI(0, 1, bias1) EPI(1, 1, bias1) EPI(2, 1, bias1) EPI(3, 1, bias1)
}

// ================= Phase 2: MFMA recurrence (cross-step pipelined) ==========
// wave w owns rows [64w, 64w+64). B-frag(c,n): W[64w+16c+(l&15)][32n+8(l>>4)+e].
// A-frag(n): h[32n+8(l>>4)+e] replicated -> D rows identical.
// Consumption order: 8,9,10,11 (L2-staged, prev-step data) -> reload issue ->
// 0..7 (AGPR) -> 12..15 (LDS). Accumulators acc_c sum all 16 chunks.

#define REPB(M, c) M(c,0) M(c,1) M(c,2) M(c,3) M(c,4) M(c,5) M(c,6) M(c,7)

#define DECLB(c, n) f16x8 bf##c##_##n;
#define LOADB(c, n)                                        \
  {                                                        \
    const float* p = wr##c + 32 * n;                       \
    bf##c##_##n = pk8(*(const float4*)p, *(const float4*)(p + 4)); \
  }
#define STOREB(c, n)                                                        \
  {                                                                         \
    const float* p = wr##c + 32 * n;                                        \
    *(f16x8*)(ldsm + (((n) - 12) * 4 + c) * 8192 + (tid << 4)) =            \
        pk8(*(const float4*)p, *(const float4*)(p + 4));                    \
  }

#define DECLS(n) f16x8 sv0_##n, sv1_##n, sv2_##n, sv3_##n;
#define LOADS(n)                                   \
  sv0_##n = wsp[((n - 8) * 4 + 0) * 512];          \
  sv1_##n = wsp[((n - 8) * 4 + 1) * 512];          \
  sv2_##n = wsp[((n - 8) * 4 + 2) * 512];          \
  sv3_##n = wsp[((n - 8) * 4 + 3) * 512];

#define MF(c, n) \
  d##c = __builtin_amdgcn_mfma_f32_16x16x32_f16(acur, bf##c##_##n, d##c, 0, 0, 0);
#define MSV(c, n) \
  d##c = __builtin_amdgcn_mfma_f32_16x16x32_f16(acur, sv##c##_##n, d##c, 0, 0, 0);
#define MFL(c, n)                                                              \
  {                                                                            \
    f16x8 bl = *(const f16x8*)(ldsm + (((n) - 12) * 4 + c) * 8192 + (tid << 4)); \
    d##c = __builtin_amdgcn_mfma_f32_16x16x32_f16(acur, bl, d##c, 0, 0, 0);    \
  }

// slot macros: consume chunk n, prefetch A-frag of chunk nn (physical index)
#define CH(n, nn)                                                \
  {                                                              \
    f16x8 anx = *(const f16x8*)(hcv + 64 * (nn) + goff);         \
    MF(0, n) MF(1, n) MF(2, n) MF(3, n)                          \
    acur = anx;                                                  \
  }
#define CSV(n, nn)                                               \
  {                                                              \
    f16x8 anx = *(const f16x8*)(hcv + 64 * (nn) + goff);         \
    MSV(0, n) MSV(1, n) MSV(2, n) MSV(3, n)                      \
    acur = anx;                                                  \
  }
#define CHL(n, nn)                                               \
  {                                                              \
    f16x8 anx = *(const f16x8*)(hcv + 64 * (nn) + goff);         \
    MFL(0, n) MFL(1, n) MFL(2, n) MFL(3, n)                      \
    acur = anx;                                                  \
  }

#define WLDS_BYTES (16 * 8192)             // 131072 (chunks 12..15)
#define HBUF0 WLDS_BYTES
#define LDS_TOTAL (WLDS_BYTES + 3 * 1024)  // 134144

// lgkm-only barrier: h-buffer ordering without draining VMEM (reloads and
// h-store acks stay in flight across the step boundary).
#define BAR()                                              \
  asm volatile("s_waitcnt lgkmcnt(0)" ::: "memory");       \
  __builtin_amdgcn_sched_barrier(0);                       \
  __builtin_amdgcn_s_barrier();                            \
  __builtin_amdgcn_sched_barrier(0);

__global__ __attribute__((amdgpu_flat_work_group_size(512, 512),
                          amdgpu_waves_per_eu(2, 2)))
void rnn_scan(const float* __restrict__ Whh, const f16x8* __restrict__ ws,
              float* __restrict__ io) {
  extern __shared__ __align__(16) char ldsm[];
  const int tid = threadIdx.x;
  const int b = blockIdx.x;
  const int l = tid & 63;
  const int w = tid >> 6;
  const int m16 = l & 15;
  const int gh = l >> 4;
  const int goff = gh << 4;
  const int rb = w << 6;
  const int jo = rb + l;

  const float* wr0 = Whh + (size_t)(rb + 0 + m16) * KDIM + 8 * gh;
  const float* wr1 = Whh + (size_t)(rb + 16 + m16) * KDIM + 8 * gh;
  const float* wr2 = Whh + (size_t)(rb + 32 + m16) * KDIM + 8 * gh;
  const float* wr3 = Whh + (size_t)(rb + 48 + m16) * KDIM + 8 * gh;
  const f16x8* wsp = ws + (w * 64 + l);

  // chunks 0..7 -> AGPR-resident (load once, fp32 -> f16)
  REPB(DECLB, 0) REPB(DECLB, 1) REPB(DECLB, 2) REPB(DECLB, 3)
  REPB(LOADB, 0) REPB(LOADB, 1) REPB(LOADB, 2) REPB(LOADB, 3)

  // chunks 8..11 staging regs: prologue load (data for step 0)
  DECLS(8) DECLS(9) DECLS(10) DECLS(11)
  LOADS(8) LOADS(9) LOADS(10) LOADS(11)

  // chunks 12..15 -> LDS (128 KB)
  STOREB(0, 12) STOREB(1, 12) STOREB(2, 12) STOREB(3, 12)
  STOREB(0, 13) STOREB(1, 13) STOREB(2, 13) STOREB(3, 13)
  STOREB(0, 14) STOREB(1, 14) STOREB(2, 14) STOREB(3, 14)
  STOREB(0, 15) STOREB(1, 15) STOREB(2, 15) STOREB(3, 15)

  if (tid < 512) ((unsigned short*)(ldsm + HBUF0))[tid] = 0;
  __syncthreads();

  char* hcur = ldsm + HBUF0;
  char* hnxt = ldsm + HBUF0 + 1024;
  char* hthr = ldsm + HBUF0 + 2048;

  float* iorow = io + (size_t)b * HDIM;

  for (int t = 0; t < SEQ_T; ++t) {
    float uin = iorow[jo];  // HBM prefetch; consumed in tail

    const char* hcv = hcur;
    f16x8 acur = *(const f16x8*)(hcv + 64 * 8 + goff);  // A-frag of chunk 8

    f32x4 d0 = {0.f, 0.f, 0.f, 0.f};
    f32x4 d1 = {0.f, 0.f, 0.f, 0.f};
    f32x4 d2 = {0.f, 0.f, 0.f, 0.f};
    f32x4 d3 = {0.f, 0.f, 0.f, 0.f};

    // 1) consume L2-staged chunks (loaded during previous step)
    CSV(8, 9) CSV(9, 10) CSV(10, 11) CSV(11, 0)
    // 2) issue reloads for step t+1 (~12 slots of cover ahead)
    LOADS(8) LOADS(9) LOADS(10) LOADS(11)
    // 3) AGPR-resident chunks
    CH(0, 1)  CH(1, 2)  CH(2, 3)  CH(3, 4)
    CH(4, 5)  CH(5, 6)  CH(6, 7)  CH(7, 12)
    // 4) LDS-resident chunks
    CHL(12, 13) CHL(13, 14) CHL(14, 15) CHL(15, 15)

    float za = (l & 16) ? d1[0] : d0[0];
    float zb = (l & 16) ? d3[0] : d2[0];
    float zs = (l & 32) ? zb : za;

    float z = uin + zs;
    float e = __expf(2.0f * z);
    float hn = 1.0f - 2.0f * __builtin_amdgcn_rcpf(e + 1.0f);  // tanh(z)
    iorow[jo] = hn;
    *(__fp16*)(hnxt + 2 * jo) = (__fp16)hn;

    char* tmp = hcur;
    hcur = hnxt; hnxt = hthr; hthr = tmp;
    iorow += (size_t)BATCH * HDIM;
    BAR();
  }
}

extern "C" void kernel_launch(void* const* d_in, const int* in_sizes, int n_in,
                              void* d_out, int out_size, void* d_ws, size_t ws_size,
                              hipStream_t stream) {
  const float* x = (const float*)d_in[0];
  const float* Wih = (const float*)d_in[1];
  const float* Whh = (const float*)d_in[2];
  const float* bih = (const float*)d_in[3];
  const float* bhh = (const float*)d_in[4];
  float* out = (float*)d_out;
  f16x8* ws = (f16x8*)d_ws;

  (void)hipFuncSetAttribute((const void*)rnn_scan,
                            hipFuncAttributeMaxDynamicSharedMemorySize,
                            LDS_TOTAL);

  w_prep<<<32, 256, 0, stream>>>(Whh, ws);

  const int M = SEQ_T * BATCH;
  dim3 g1((M / 128) * (HDIM / 64));  // 8192
  xw_gemm<<<g1, 256, 0, stream>>>(x, Wih, bih, bhh, out);

  rnn_scan<<<BATCH, 512, LDS_TOTAL, stream>>>(Whh, ws, out);
}